// Round 1
// baseline (913.987 us; speedup 1.0000x reference)
//
#include <hip/hip_runtime.h>

#define E   128
#define HD  32
#define NB  512
#define NN  65536
#define TT  (NB + NN)   // 66048 tokens: [0,NB) metal, [NB,TT) nodes

// Row gather: if metal != nullptr, token t<NB comes from metal[t], else base[t-NB].
// If metal == nullptr, contiguous token-indexed array.
__device__ __forceinline__ const float* row_ptr(const float* base, const float* metal, int t) {
  return metal ? ((t < NB) ? metal + (size_t)t * E : base + (size_t)(t - NB) * E)
               : base + (size_t)t * E;
}
__device__ __forceinline__ float* row_ptr_w(float* base, float* metal, int t) {
  return metal ? ((t < NB) ? metal + (size_t)t * E : base + (size_t)(t - NB) * E)
               : base + (size_t)t * E;
}

// start[b] = first node index of graph b (batch is sorted); start[NB] = NN.
__global__ void k_starts(const int* __restrict__ batch, int* __restrict__ start) {
  int i = blockIdx.x * blockDim.x + threadIdx.x;
  if (i >= NN) return;
  int bi = batch[i];
  int bp = (i == 0) ? -1 : batch[i - 1];
  for (int b = bp + 1; b <= bi; ++b) start[b] = i;
  if (i == NN - 1)
    for (int b = bi + 1; b <= NB; ++b) start[b] = NN;
}

// C[t][j] = act( bias[j] + sum_k A[t][k] * W[j][k] )   (i.e. C = A @ W^T + b)
// Block: 32 rows x 128 cols, 256 threads, 4x4 micro-tile, k-vectorized float4.
template <bool RELU>
__global__ __launch_bounds__(256, 4)
void k_gemm(const float* __restrict__ Ax, const float* __restrict__ Am,
            const float* __restrict__ W, const float* __restrict__ bias,
            float* __restrict__ Cx, float* __restrict__ Cm) {
  __shared__ float Alds[32][E];    // 16 KB, row-major (k contiguous)
  __shared__ float Wlds[E][36];    // 18 KB, 36 = 32 + pad, 144B row stride (16B aligned)
  const int tid = threadIdx.x;
  const int t0 = blockIdx.x * 32;

  // Stage A tile: 32 rows x 128 floats = 1024 float4, 4 per thread, coalesced.
  #pragma unroll
  for (int u = 0; u < 4; ++u) {
    int e4 = tid + u * 256;
    int m = e4 >> 5, k4 = e4 & 31;
    const float* ap = row_ptr(Ax, Am, t0 + m);
    float4 v = ((const float4*)ap)[k4];
    *(float4*)&Alds[m][k4 * 4] = v;
  }

  float acc[4][4];
  #pragma unroll
  for (int i = 0; i < 4; ++i)
    #pragma unroll
    for (int u = 0; u < 4; ++u) acc[i][u] = 0.f;

  const int c = tid & 31;   // col group: cols c, c+32, c+64, c+96
  const int r = tid >> 5;   // row group: rows 4r..4r+3

  for (int kc = 0; kc < 4; ++kc) {
    __syncthreads();  // A ready (kc=0) / previous chunk's compute done with Wlds
    // Stage W k-chunk: rows 0..127, cols kc*32..kc*32+31 (8 float4 per row).
    #pragma unroll
    for (int u = 0; u < 4; ++u) {
      int e4 = tid + u * 256;
      int j = e4 >> 3, k4 = e4 & 7;
      float4 v = *(const float4*)&W[j * E + kc * 32 + k4 * 4];
      *(float4*)&Wlds[j][k4 * 4] = v;
    }
    __syncthreads();
    const int kb = kc * 32;
    #pragma unroll
    for (int kk = 0; kk < 32; kk += 4) {
      float4 a[4], w[4];
      #pragma unroll
      for (int i = 0; i < 4; ++i) a[i] = *(const float4*)&Alds[4 * r + i][kb + kk];
      #pragma unroll
      for (int u = 0; u < 4; ++u) w[u] = *(const float4*)&Wlds[c + 32 * u][kk];
      #pragma unroll
      for (int i = 0; i < 4; ++i)
        #pragma unroll
        for (int u = 0; u < 4; ++u) {
          acc[i][u] = fmaf(a[i].x, w[u].x, acc[i][u]);
          acc[i][u] = fmaf(a[i].y, w[u].y, acc[i][u]);
          acc[i][u] = fmaf(a[i].z, w[u].z, acc[i][u]);
          acc[i][u] = fmaf(a[i].w, w[u].w, acc[i][u]);
        }
    }
  }

  #pragma unroll
  for (int i = 0; i < 4; ++i) {
    float* cp = row_ptr_w(Cx, Cm, t0 + 4 * r + i);
    #pragma unroll
    for (int u = 0; u < 4; ++u) {
      int j = c + 32 * u;
      float vv = acc[i][u] + bias[j];
      if (RELU) vv = fmaxf(vv, 0.f);
      cp[j] = vv;
    }
  }
}

// Per-graph attention, online softmax. grid = (NB, 4); block = 256 (4 waves = 4 heads).
// Lane = one query token; keys streamed (wave-uniform addresses -> scalar loads).
__global__ __launch_bounds__(256, 4)
void k_attn(const float* __restrict__ Q, const float* __restrict__ K,
            const float* __restrict__ V, const int* __restrict__ start,
            float* __restrict__ ctx) {
  const int g = blockIdx.x;
  const int h = threadIdx.x >> 6;
  const int lane = threadIdx.x & 63;
  const int s0 = start[g];
  const int c = start[g + 1] - s0 + 1;  // tokens in graph incl. metal at slot 0
  const float scale = 0.17677669529663687f;  // 1/sqrt(32)

  for (int q0 = 64 * blockIdx.y; q0 < c; q0 += 64 * 4) {
    const int qi = q0 + lane;
    const bool act = qi < c;
    const int tq = (!act || qi == 0) ? g : (NB + s0 + qi - 1);

    float qv[HD];
    {
      const float* qp = Q + (size_t)tq * E + h * HD;
      #pragma unroll
      for (int j = 0; j < HD; j += 4) {
        float4 t = *(const float4*)(qp + j);
        qv[j] = t.x; qv[j + 1] = t.y; qv[j + 2] = t.z; qv[j + 3] = t.w;
      }
    }

    float mrun = -3.0e38f, l = 0.f;
    float o[HD];
    #pragma unroll
    for (int j = 0; j < HD; ++j) o[j] = 0.f;

    for (int m = 0; m < c; ++m) {
      const int tm = (m == 0) ? g : (NB + s0 + m - 1);
      const float* kp = K + (size_t)tm * E + h * HD;
      float s = 0.f;
      #pragma unroll
      for (int j = 0; j < HD; j += 4) {
        float4 kv = *(const float4*)(kp + j);
        s = fmaf(qv[j], kv.x, s);
        s = fmaf(qv[j + 1], kv.y, s);
        s = fmaf(qv[j + 2], kv.z, s);
        s = fmaf(qv[j + 3], kv.w, s);
      }
      s *= scale;
      const float mn = fmaxf(mrun, s);
      const float alpha = __expf(mrun - mn);
      const float p = __expf(s - mn);
      l = l * alpha + p;
      const float* vp = V + (size_t)tm * E + h * HD;
      #pragma unroll
      for (int j = 0; j < HD; j += 4) {
        float4 vv = *(const float4*)(vp + j);
        o[j]     = fmaf(o[j],     alpha, p * vv.x);
        o[j + 1] = fmaf(o[j + 1], alpha, p * vv.y);
        o[j + 2] = fmaf(o[j + 2], alpha, p * vv.z);
        o[j + 3] = fmaf(o[j + 3], alpha, p * vv.w);
      }
      mrun = mn;
    }

    if (act) {
      const float inv = 1.f / l;
      float* op = ctx + (size_t)tq * E + h * HD;
      #pragma unroll
      for (int j = 0; j < HD; j += 4) {
        float4 t;
        t.x = o[j] * inv; t.y = o[j + 1] * inv;
        t.z = o[j + 2] * inv; t.w = o[j + 3] * inv;
        *(float4*)(op + j) = t;
      }
    }
  }
}

extern "C" void kernel_launch(void* const* d_in, const int* in_sizes, int n_in,
                              void* d_out, int out_size, void* d_ws, size_t ws_size,
                              hipStream_t stream) {
  const float* x       = (const float*)d_in[0];
  const float* metal_x = (const float*)d_in[1];
  const int*   batch   = (const int*)d_in[2];
  const float* Wk      = (const float*)d_in[3];
  const float* bk      = (const float*)d_in[4];
  const float* Wq      = (const float*)d_in[5];
  const float* bq      = (const float*)d_in[6];
  const float* in_w    = (const float*)d_in[7];
  const float* in_b    = (const float*)d_in[8];
  const float* out_w   = (const float*)d_in[9];
  const float* out_b   = (const float*)d_in[10];
  float* out = (float*)d_out;

  int* start = (int*)d_ws;
  float* ws = (float*)d_ws;
  const size_t TE = (size_t)TT * E;
  float* bufV = ws + 1024;        // V
  float* bufA = bufV + TE;        // Hq, then K
  float* bufB = bufA + TE;        // Hk, then ctx
  float* bufQ = bufB + TE;        // Q
  // total ws use: 4 KB + 4 * 66048*128*4 B ~= 135.3 MB

  k_starts<<<NN / 256, 256, 0, stream>>>(batch, start);

  const int gblocks = TT / 32;  // 2064, TT divisible by 32
  // V = val @ in_w[2E:].T + in_b[2E:]
  k_gemm<false><<<gblocks, 256, 0, stream>>>(x, metal_x, in_w + 2 * E * E, in_b + 2 * E, bufV, nullptr);
  // Hq = relu(val @ Wq.T + bq)
  k_gemm<true><<<gblocks, 256, 0, stream>>>(x, metal_x, Wq, bq, bufA, nullptr);
  // Hk = relu(val @ Wk.T + bk)
  k_gemm<true><<<gblocks, 256, 0, stream>>>(x, metal_x, Wk, bk, bufB, nullptr);
  // Q = Hq @ in_w[:E].T + in_b[:E]
  k_gemm<false><<<gblocks, 256, 0, stream>>>(bufA, nullptr, in_w, in_b, bufQ, nullptr);
  // K = Hk @ in_w[E:2E].T + in_b[E:2E]   (overwrites Hq slot)
  k_gemm<false><<<gblocks, 256, 0, stream>>>(bufB, nullptr, in_w + E * E, in_b + E, bufA, nullptr);

  dim3 agrid(NB, 4);
  k_attn<<<agrid, 256, 0, stream>>>(bufQ, bufA, bufV, start, bufB);  // ctx -> bufB

  // out = ctx @ out_w.T + out_b, scattered: nodes -> d_out[0:NN*E), metal -> d_out[NN*E:)
  k_gemm<false><<<gblocks, 256, 0, stream>>>(bufB, nullptr, out_w, out_b, out, out + (size_t)NN * E);
}

// Round 2
// 530.616 us; speedup vs baseline: 1.7225x; 1.7225x over previous
//
#include <hip/hip_runtime.h>

#define E   128
#define HD  32
#define NB  512
#define NN  65536
#define TT  (NB + NN)   // 66048 tokens: [0,NB) metal, [NB,TT) nodes

__device__ __forceinline__ const float* row_ptr(const float* base, const float* metal, int t) {
  return metal ? ((t < NB) ? metal + (size_t)t * E : base + (size_t)(t - NB) * E)
               : base + (size_t)t * E;
}
__device__ __forceinline__ float* row_ptr_w(float* base, float* metal, int t) {
  return metal ? ((t < NB) ? metal + (size_t)t * E : base + (size_t)(t - NB) * E)
               : base + (size_t)t * E;
}

// start[b] = first node index of graph b (batch is sorted); start[NB] = NN.
__global__ void k_starts(const int* __restrict__ batch, int* __restrict__ start) {
  int i = blockIdx.x * blockDim.x + threadIdx.x;
  if (i >= NN) return;
  int bi = batch[i];
  int bp = (i == 0) ? -1 : batch[i - 1];
  for (int b = bp + 1; b <= bi; ++b) start[b] = i;
  if (i == NN - 1)
    for (int b = bi + 1; b <= NB; ++b) start[b] = NN;
}

// C[t][j] = act( bias[j] + sum_k A[t][k] * W[j][k] )   (i.e. C = A @ W^T + b)
template <bool RELU>
__global__ __launch_bounds__(256, 4)
void k_gemm(const float* __restrict__ Ax, const float* __restrict__ Am,
            const float* __restrict__ W, const float* __restrict__ bias,
            float* __restrict__ Cx, float* __restrict__ Cm) {
  __shared__ float Alds[32][E];
  __shared__ float Wlds[E][36];
  const int tid = threadIdx.x;
  const int t0 = blockIdx.x * 32;

  #pragma unroll
  for (int u = 0; u < 4; ++u) {
    int e4 = tid + u * 256;
    int m = e4 >> 5, k4 = e4 & 31;
    const float* ap = row_ptr(Ax, Am, t0 + m);
    float4 v = ((const float4*)ap)[k4];
    *(float4*)&Alds[m][k4 * 4] = v;
  }

  float acc[4][4];
  #pragma unroll
  for (int i = 0; i < 4; ++i)
    #pragma unroll
    for (int u = 0; u < 4; ++u) acc[i][u] = 0.f;

  const int c = tid & 31;
  const int r = tid >> 5;

  for (int kc = 0; kc < 4; ++kc) {
    __syncthreads();
    #pragma unroll
    for (int u = 0; u < 4; ++u) {
      int e4 = tid + u * 256;
      int j = e4 >> 3, k4 = e4 & 7;
      float4 v = *(const float4*)&W[j * E + kc * 32 + k4 * 4];
      *(float4*)&Wlds[j][k4 * 4] = v;
    }
    __syncthreads();
    const int kb = kc * 32;
    #pragma unroll
    for (int kk = 0; kk < 32; kk += 4) {
      float4 a[4], w[4];
      #pragma unroll
      for (int i = 0; i < 4; ++i) a[i] = *(const float4*)&Alds[4 * r + i][kb + kk];
      #pragma unroll
      for (int u = 0; u < 4; ++u) w[u] = *(const float4*)&Wlds[c + 32 * u][kk];
      #pragma unroll
      for (int i = 0; i < 4; ++i)
        #pragma unroll
        for (int u = 0; u < 4; ++u) {
          acc[i][u] = fmaf(a[i].x, w[u].x, acc[i][u]);
          acc[i][u] = fmaf(a[i].y, w[u].y, acc[i][u]);
          acc[i][u] = fmaf(a[i].z, w[u].z, acc[i][u]);
          acc[i][u] = fmaf(a[i].w, w[u].w, acc[i][u]);
        }
    }
  }

  #pragma unroll
  for (int i = 0; i < 4; ++i) {
    float* cp = row_ptr_w(Cx, Cm, t0 + 4 * r + i);
    #pragma unroll
    for (int u = 0; u < 4; ++u) {
      int j = c + 32 * u;
      float vv = acc[i][u] + bias[j];
      if (RELU) vv = fmaxf(vv, 0.f);
      cp[j] = vv;
    }
  }
}

// Per-graph attention, online softmax, LDS-staged K/V key-chunks.
// grid = (NB, 4); block = 256 (4 waves = 4 heads); lane = query.
// Key chunk of 32 slots staged coalesced into LDS; inner loop reads LDS
// broadcast (wave-uniform address -> conflict-free, ~5 cy) instead of
// latency-serialized global broadcasts.
__global__ __launch_bounds__(256, 4)
void k_attn(const float* __restrict__ Q, const float* __restrict__ K,
            const float* __restrict__ V, const int* __restrict__ start,
            float* __restrict__ ctx) {
  __shared__ float Klds[32][E];   // 16 KB
  __shared__ float Vlds[32][E];   // 16 KB
  const int g = blockIdx.x;
  const int tid = threadIdx.x;
  const int h = tid >> 6;
  const int lane = tid & 63;
  const int s0 = start[g];
  const int c = start[g + 1] - s0 + 1;  // tokens incl. metal at slot 0
  const float scale = 0.17677669529663687f;  // 1/sqrt(32)

  for (int q0 = 64 * blockIdx.y; q0 < c; q0 += 64 * 4) {
    const int qi = q0 + lane;
    const bool act = qi < c;
    const int tq = (!act || qi == 0) ? g : (NB + s0 + qi - 1);

    float qv[HD];
    {
      const float* qp = Q + (size_t)tq * E + h * HD;
      #pragma unroll
      for (int j = 0; j < HD; j += 4) {
        float4 t = *(const float4*)(qp + j);
        qv[j] = t.x * scale; qv[j + 1] = t.y * scale;
        qv[j + 2] = t.z * scale; qv[j + 3] = t.w * scale;
      }
    }

    float mrun = -3.0e38f, l = 0.f;
    float o[HD];
    #pragma unroll
    for (int j = 0; j < HD; ++j) o[j] = 0.f;

    const int nch = (c + 31) >> 5;
    for (int ch = 0; ch < nch; ++ch) {
      const int base = ch * 32;
      __syncthreads();  // previous chunk's compute done with LDS
      // Stage 32 key slots (K and V, all heads): 2 x 1024 float4, coalesced.
      #pragma unroll
      for (int u = 0; u < 4; ++u) {
        int e4 = tid + u * 256;
        int mrow = e4 >> 5, col4 = e4 & 31;
        int slot = base + mrow;
        if (slot < c) {
          int tm = (slot == 0) ? g : (NB + s0 + slot - 1);
          const float4* kp = (const float4*)(K + (size_t)tm * E);
          const float4* vp = (const float4*)(V + (size_t)tm * E);
          *(float4*)&Klds[mrow][col4 * 4] = kp[col4];
          *(float4*)&Vlds[mrow][col4 * 4] = vp[col4];
        }
      }
      __syncthreads();

      const int mmax = min(32, c - base);
      for (int m = 0; m < mmax; ++m) {
        const float* kp = &Klds[m][h * HD];
        float s = 0.f;
        #pragma unroll
        for (int j = 0; j < HD; j += 4) {
          float4 kv = *(const float4*)(kp + j);
          s = fmaf(qv[j], kv.x, s);
          s = fmaf(qv[j + 1], kv.y, s);
          s = fmaf(qv[j + 2], kv.z, s);
          s = fmaf(qv[j + 3], kv.w, s);
        }
        const float mn = fmaxf(mrun, s);
        const float alpha = __expf(mrun - mn);
        const float p = __expf(s - mn);
        l = l * alpha + p;
        const float* vp = &Vlds[m][h * HD];
        #pragma unroll
        for (int j = 0; j < HD; j += 4) {
          float4 vv = *(const float4*)(vp + j);
          o[j]     = fmaf(o[j],     alpha, p * vv.x);
          o[j + 1] = fmaf(o[j + 1], alpha, p * vv.y);
          o[j + 2] = fmaf(o[j + 2], alpha, p * vv.z);
          o[j + 3] = fmaf(o[j + 3], alpha, p * vv.w);
        }
        mrun = mn;
      }
    }

    if (act) {
      const float inv = 1.f / l;
      float* op = ctx + (size_t)tq * E + h * HD;
      #pragma unroll
      for (int j = 0; j < HD; j += 4) {
        float4 t;
        t.x = o[j] * inv; t.y = o[j + 1] * inv;
        t.z = o[j + 2] * inv; t.w = o[j + 3] * inv;
        *(float4*)(op + j) = t;
      }
    }
  }
}

extern "C" void kernel_launch(void* const* d_in, const int* in_sizes, int n_in,
                              void* d_out, int out_size, void* d_ws, size_t ws_size,
                              hipStream_t stream) {
  const float* x       = (const float*)d_in[0];
  const float* metal_x = (const float*)d_in[1];
  const int*   batch   = (const int*)d_in[2];
  const float* Wk      = (const float*)d_in[3];
  const float* bk      = (const float*)d_in[4];
  const float* Wq      = (const float*)d_in[5];
  const float* bq      = (const float*)d_in[6];
  const float* in_w    = (const float*)d_in[7];
  const float* in_b    = (const float*)d_in[8];
  const float* out_w   = (const float*)d_in[9];
  const float* out_b   = (const float*)d_in[10];
  float* out = (float*)d_out;

  int* start = (int*)d_ws;
  float* ws = (float*)d_ws;
  const size_t TE = (size_t)TT * E;
  float* bufV = ws + 1024;        // V
  float* bufA = bufV + TE;        // Hq, then K
  float* bufB = bufA + TE;        // Hk, then ctx
  float* bufQ = bufB + TE;        // Q

  k_starts<<<NN / 256, 256, 0, stream>>>(batch, start);

  const int gblocks = TT / 32;  // 2064
  k_gemm<false><<<gblocks, 256, 0, stream>>>(x, metal_x, in_w + 2 * E * E, in_b + 2 * E, bufV, nullptr);
  k_gemm<true><<<gblocks, 256, 0, stream>>>(x, metal_x, Wq, bq, bufA, nullptr);
  k_gemm<true><<<gblocks, 256, 0, stream>>>(x, metal_x, Wk, bk, bufB, nullptr);
  k_gemm<false><<<gblocks, 256, 0, stream>>>(bufA, nullptr, in_w, in_b, bufQ, nullptr);
  k_gemm<false><<<gblocks, 256, 0, stream>>>(bufB, nullptr, in_w + E * E, in_b + E, bufA, nullptr);

  dim3 agrid(NB, 4);
  k_attn<<<agrid, 256, 0, stream>>>(bufQ, bufA, bufV, start, bufB);  // ctx -> bufB

  k_gemm<false><<<gblocks, 256, 0, stream>>>(bufB, nullptr, out_w, out_b, out, out + (size_t)NN * E);
}

// Round 4
// 361.493 us; speedup vs baseline: 2.5284x; 1.4678x over previous
//
#include <hip/hip_runtime.h>

#define E   128
#define HD  32
#define NB  512
#define NN  65536
#define TT  (NB + NN)   // 66048 tokens: [0,NB) metal, [NB,TT) nodes

typedef __attribute__((ext_vector_type(8))) short short8;
typedef __attribute__((ext_vector_type(4))) float f32x4;

__device__ __forceinline__ const float* row_ptr(const float* base, const float* metal, int t) {
  return metal ? ((t < NB) ? metal + (size_t)t * E : base + (size_t)(t - NB) * E)
               : base + (size_t)t * E;
}
__device__ __forceinline__ float* row_ptr_w(float* base, float* metal, int t) {
  return metal ? ((t < NB) ? metal + (size_t)t * E : base + (size_t)(t - NB) * E)
               : base + (size_t)t * E;
}

__device__ __forceinline__ unsigned short f2bf_rne(float x) {
  unsigned u = __float_as_uint(x);
  return (unsigned short)((u + 0x7FFFu + ((u >> 16) & 1u)) >> 16);
}
// x ~= hi + lo with hi,lo bf16 (split-bf16 for fp32-accurate MFMA)
__device__ __forceinline__ void split_bf(float x, unsigned short& h, unsigned short& l) {
  h = f2bf_rne(x);
  float hf = __uint_as_float(((unsigned)h) << 16);
  l = f2bf_rne(x - hf);
}

// start[b] = first node index of graph b (batch is sorted); start[NB] = NN.
__global__ void k_starts(const int* __restrict__ batch, int* __restrict__ start) {
  int i = blockIdx.x * blockDim.x + threadIdx.x;
  if (i >= NN) return;
  int bi = batch[i];
  int bp = (i == 0) ? -1 : batch[i - 1];
  for (int b = bp + 1; b <= bi; ++b) start[b] = i;
  if (i == NN - 1)
    for (int b = bi + 1; b <= NB; ++b) start[b] = NN;
}

// Split all weights into hi/lo bf16. Row layout in Wh/Wl ([768][128]):
// [0,128) Wq | [128,256) Wk | [256,640) in_w | [640,768) out_w
__global__ void k_wconv(const float* __restrict__ Wq, const float* __restrict__ Wk,
                        const float* __restrict__ in_w, const float* __restrict__ out_w,
                        unsigned short* __restrict__ Wh, unsigned short* __restrict__ Wl) {
  int idx = blockIdx.x * 256 + threadIdx.x;   // < 768*128
  int r = idx >> 7, c = idx & 127;
  float v;
  if (r < 128)      v = Wq[r * 128 + c];
  else if (r < 256) v = Wk[(r - 128) * 128 + c];
  else if (r < 640) v = in_w[(r - 256) * 128 + c];
  else              v = out_w[(r - 640) * 128 + c];
  unsigned short h, l;
  split_bf(v, h, l);
  Wh[idx] = h;
  Wl[idx] = l;
}

// C[t][j] = act( bias[j] + sum_k A[t][k] * W[j][k] ) via split-bf16 MFMA.
// Block: 128x128 tile, 4 waves (32 rows each), K in 4 chunks of 32.
template <bool RELU>
__global__ __launch_bounds__(256, 2)
void k_gemm_mfma(const float* __restrict__ Ax, const float* __restrict__ Am,
                 const unsigned short* __restrict__ Wh, const unsigned short* __restrict__ Wl,
                 const float* __restrict__ bias,
                 float* __restrict__ Cx, float* __restrict__ Cm) {
  __shared__ float Alds[128][36];            // 18 KB
  __shared__ unsigned short WldsH[128][40];  // 10 KB
  __shared__ unsigned short WldsL[128][40];  // 10 KB
  const int tid = threadIdx.x;
  const int wave = tid >> 6;
  const int lane = tid & 63;
  const int lrow = lane & 15;
  const int q = lane >> 4;        // quad 0..3
  const int t0 = blockIdx.x * 128;

  f32x4 acc[2][8];
  #pragma unroll
  for (int mt = 0; mt < 2; ++mt)
    #pragma unroll
    for (int nt = 0; nt < 8; ++nt) acc[mt][nt] = (f32x4){0.f, 0.f, 0.f, 0.f};

  for (int ks = 0; ks < 4; ++ks) {
    __syncthreads();
    // Stage A slice: 128 rows x 32 floats (k = ks*32..+32), 4 float4/thread.
    #pragma unroll
    for (int u = 0; u < 4; ++u) {
      int e4 = tid + u * 256;           // [0,1024)
      int m = e4 >> 3, k4 = e4 & 7;
      const float* rp = row_ptr(Ax, Am, t0 + m);
      float4 v = ((const float4*)(rp + ks * 32))[k4];
      *(float4*)&Alds[m][k4 * 4] = v;
    }
    // Stage W hi/lo slices: 2 x 128 rows x 32 bf16, 16B/thread x 4.
    #pragma unroll
    for (int u = 0; u < 4; ++u) {
      int idx = tid + u * 256;          // [0,1024)
      int half = idx >> 9, rem = idx & 511;
      int j = rem >> 2, seg = rem & 3;
      const unsigned short* src = (half ? Wl : Wh) + j * 128 + ks * 32 + seg * 8;
      short8 v = *(const short8*)src;
      unsigned short* dst = (half ? &WldsL[j][seg * 8] : &WldsH[j][seg * 8]);
      *(short8*)dst = v;
    }
    __syncthreads();

    // A fragments (hi/lo): A[m = lane&15][k = q*8 + jj]
    short8 ah[2], al[2];
    #pragma unroll
    for (int mt = 0; mt < 2; ++mt) {
      int m = wave * 32 + mt * 16 + lrow;
      float4 f0 = *(const float4*)&Alds[m][q * 8];
      float4 f1 = *(const float4*)&Alds[m][q * 8 + 4];
      unsigned short h, l;
      split_bf(f0.x, h, l); ah[mt][0] = (short)h; al[mt][0] = (short)l;
      split_bf(f0.y, h, l); ah[mt][1] = (short)h; al[mt][1] = (short)l;
      split_bf(f0.z, h, l); ah[mt][2] = (short)h; al[mt][2] = (short)l;
      split_bf(f0.w, h, l); ah[mt][3] = (short)h; al[mt][3] = (short)l;
      split_bf(f1.x, h, l); ah[mt][4] = (short)h; al[mt][4] = (short)l;
      split_bf(f1.y, h, l); ah[mt][5] = (short)h; al[mt][5] = (short)l;
      split_bf(f1.z, h, l); ah[mt][6] = (short)h; al[mt][6] = (short)l;
      split_bf(f1.w, h, l); ah[mt][7] = (short)h; al[mt][7] = (short)l;
    }

    // B-frag: B[k][n] = W[n][k]; lane holds n = lane&15 (row j of W), k = q*8+jj.
    #pragma unroll
    for (int nt = 0; nt < 8; ++nt) {
      int j = nt * 16 + lrow;
      short8 bh = *(const short8*)&WldsH[j][q * 8];
      short8 bl = *(const short8*)&WldsL[j][q * 8];
      #pragma unroll
      for (int mt = 0; mt < 2; ++mt) {
        acc[mt][nt] = __builtin_amdgcn_mfma_f32_16x16x32_bf16(ah[mt], bh, acc[mt][nt], 0, 0, 0);
        acc[mt][nt] = __builtin_amdgcn_mfma_f32_16x16x32_bf16(al[mt], bh, acc[mt][nt], 0, 0, 0);
        acc[mt][nt] = __builtin_amdgcn_mfma_f32_16x16x32_bf16(ah[mt], bl, acc[mt][nt], 0, 0, 0);
      }
    }
  }

  // Epilogue. C/D layout: col = lane&15, row = q*4 + reg.
  #pragma unroll
  for (int mt = 0; mt < 2; ++mt) {
    #pragma unroll
    for (int reg = 0; reg < 4; ++reg) {
      int m = wave * 32 + mt * 16 + q * 4 + reg;
      float* cp = row_ptr_w(Cx, Cm, t0 + m);
      #pragma unroll
      for (int nt = 0; nt < 8; ++nt) {
        int j = nt * 16 + lrow;
        float v = acc[mt][nt][reg] + bias[j];
        if (RELU) v = fmaxf(v, 0.f);
        cp[j] = v;
      }
    }
  }
}

// Per-graph attention, online softmax, LDS-staged K/V key-chunks.
__global__ __launch_bounds__(256, 4)
void k_attn(const float* __restrict__ Q, const float* __restrict__ K,
            const float* __restrict__ V, const int* __restrict__ start,
            float* __restrict__ ctx) {
  __shared__ float Klds[32][E];
  __shared__ float Vlds[32][E];
  const int g = blockIdx.x;
  const int tid = threadIdx.x;
  const int h = tid >> 6;
  const int lane = tid & 63;
  const int s0 = start[g];
  const int c = start[g + 1] - s0 + 1;
  const float scale = 0.17677669529663687f;

  for (int q0 = 64 * blockIdx.y; q0 < c; q0 += 64 * 4) {
    const int qi = q0 + lane;
    const bool act = qi < c;
    const int tq = (!act || qi == 0) ? g : (NB + s0 + qi - 1);

    float qv[HD];
    {
      const float* qp = Q + (size_t)tq * E + h * HD;
      #pragma unroll
      for (int j = 0; j < HD; j += 4) {
        float4 t = *(const float4*)(qp + j);
        qv[j] = t.x * scale; qv[j + 1] = t.y * scale;
        qv[j + 2] = t.z * scale; qv[j + 3] = t.w * scale;
      }
    }

    float mrun = -3.0e38f, l = 0.f;
    float o[HD];
    #pragma unroll
    for (int j = 0; j < HD; ++j) o[j] = 0.f;

    const int nch = (c + 31) >> 5;
    for (int ch = 0; ch < nch; ++ch) {
      const int base = ch * 32;
      __syncthreads();
      #pragma unroll
      for (int u = 0; u < 4; ++u) {
        int e4 = tid + u * 256;
        int mrow = e4 >> 5, col4 = e4 & 31;
        int slot = base + mrow;
        if (slot < c) {
          int tm = (slot == 0) ? g : (NB + s0 + slot - 1);
          const float4* kp = (const float4*)(K + (size_t)tm * E);
          const float4* vp = (const float4*)(V + (size_t)tm * E);
          *(float4*)&Klds[mrow][col4 * 4] = kp[col4];
          *(float4*)&Vlds[mrow][col4 * 4] = vp[col4];
        }
      }
      __syncthreads();

      const int mmax = min(32, c - base);
      for (int m = 0; m < mmax; ++m) {
        const float* kp = &Klds[m][h * HD];
        float s = 0.f;
        #pragma unroll
        for (int j = 0; j < HD; j += 4) {
          float4 kv = *(const float4*)(kp + j);
          s = fmaf(qv[j], kv.x, s);
          s = fmaf(qv[j + 1], kv.y, s);
          s = fmaf(qv[j + 2], kv.z, s);
          s = fmaf(qv[j + 3], kv.w, s);
        }
        const float mn = fmaxf(mrun, s);
        const float alpha = __expf(mrun - mn);
        const float p = __expf(s - mn);
        l = l * alpha + p;
        const float* vp = &Vlds[m][h * HD];
        #pragma unroll
        for (int j = 0; j < HD; j += 4) {
          float4 vv = *(const float4*)(vp + j);
          o[j]     = fmaf(o[j],     alpha, p * vv.x);
          o[j + 1] = fmaf(o[j + 1], alpha, p * vv.y);
          o[j + 2] = fmaf(o[j + 2], alpha, p * vv.z);
          o[j + 3] = fmaf(o[j + 3], alpha, p * vv.w);
        }
        mrun = mn;
      }
    }

    if (act) {
      const float inv = 1.f / l;
      float* op = ctx + (size_t)tq * E + h * HD;
      #pragma unroll
      for (int j = 0; j < HD; j += 4) {
        float4 t;
        t.x = o[j] * inv; t.y = o[j + 1] * inv;
        t.z = o[j + 2] * inv; t.w = o[j + 3] * inv;
        *(float4*)(op + j) = t;
      }
    }
  }
}

extern "C" void kernel_launch(void* const* d_in, const int* in_sizes, int n_in,
                              void* d_out, int out_size, void* d_ws, size_t ws_size,
                              hipStream_t stream) {
  const float* x       = (const float*)d_in[0];
  const float* metal_x = (const float*)d_in[1];
  const int*   batch   = (const int*)d_in[2];
  const float* Wk      = (const float*)d_in[3];
  const float* bk      = (const float*)d_in[4];
  const float* Wq      = (const float*)d_in[5];
  const float* bq      = (const float*)d_in[6];
  const float* in_w    = (const float*)d_in[7];
  const float* in_b    = (const float*)d_in[8];
  const float* out_w   = (const float*)d_in[9];
  const float* out_b   = (const float*)d_in[10];
  float* out = (float*)d_out;

  float* ws = (float*)d_ws;
  int* start = (int*)d_ws;                            // 513 ints (pad to 528 floats)
  unsigned short* Wh = (unsigned short*)(ws + 528);   // 768*128 shorts = 49152 floats
  unsigned short* Wl = Wh + 768 * 128;                // another 49152 floats
  const size_t TE = (size_t)TT * E;
  // Weights occupy 98304 floats total; buffers start AFTER both halves.
  float* bufV = ws + 528 + 98304;   // V
  float* bufA = bufV + TE;          // Hq, then K
  float* bufB = bufA + TE;          // Hk, then ctx
  float* bufQ = out;                // Q staged in d_out (rewritten by final GEMM)
  // ws use: (528 + 98304 + 3*TE)*4 B ~= 101.8 MB  (< 135.3 MB known-good)

  k_starts<<<NN / 256, 256, 0, stream>>>(batch, start);
  k_wconv<<<768 * 128 / 256, 256, 0, stream>>>(Wq, Wk, in_w, out_w, Wh, Wl);

  const int gblocks = TT / 128;  // 516
  // row offsets into Wh/Wl: Wq=0, Wk=128, in_w q=256 k=384 v=512, out_w=640
  k_gemm_mfma<false><<<gblocks, 256, 0, stream>>>(x, metal_x, Wh + 512 * 128, Wl + 512 * 128, in_b + 256, bufV, nullptr);
  k_gemm_mfma<true ><<<gblocks, 256, 0, stream>>>(x, metal_x, Wh,             Wl,             bq,         bufA, nullptr);
  k_gemm_mfma<true ><<<gblocks, 256, 0, stream>>>(x, metal_x, Wh + 128 * 128, Wl + 128 * 128, bk,         bufB, nullptr);
  k_gemm_mfma<false><<<gblocks, 256, 0, stream>>>(bufA, nullptr, Wh + 256 * 128, Wl + 256 * 128, in_b,       bufQ, nullptr);
  k_gemm_mfma<false><<<gblocks, 256, 0, stream>>>(bufB, nullptr, Wh + 384 * 128, Wl + 384 * 128, in_b + 128, bufA, nullptr);

  dim3 agrid(NB, 4);
  k_attn<<<agrid, 256, 0, stream>>>(bufQ, bufA, bufV, start, bufB);  // ctx -> bufB

  k_gemm_mfma<false><<<gblocks, 256, 0, stream>>>(bufB, nullptr, Wh + 640 * 128, Wl + 640 * 128, out_b, out, out + (size_t)NN * E);
}

// Round 6
// 308.620 us; speedup vs baseline: 2.9615x; 1.1713x over previous
//
#include <hip/hip_runtime.h>

#define E   128
#define HD  32
#define NB  512
#define NN  65536
#define TT  (NB + NN)   // 66048 tokens: [0,NB) metal, [NB,TT) nodes
#define TE  ((size_t)TT * 128)

typedef __attribute__((ext_vector_type(8))) short short8;
typedef __attribute__((ext_vector_type(4))) float f32x4;

enum { AF32 = 0, ASPLIT = 1 };
enum { OF32T = 0, OSPLITT = 1, OSPLITSEQ = 2, OBF16SEQ = 3 };

__device__ __forceinline__ const float* row_ptr(const float* base, const float* metal, int t) {
  return (t < NB) ? metal + (size_t)t * E : base + (size_t)(t - NB) * E;
}
__device__ __forceinline__ float* row_ptr_w(float* base, float* metal, int t) {
  return (t < NB) ? metal + (size_t)t * E : base + (size_t)(t - NB) * E;
}

__device__ __forceinline__ unsigned short f2bf_rne(float x) {
  unsigned u = __float_as_uint(x);
  return (unsigned short)((u + 0x7FFFu + ((u >> 16) & 1u)) >> 16);
}
__device__ __forceinline__ void split_bf(float x, unsigned short& h, unsigned short& l) {
  h = f2bf_rne(x);
  float hf = __uint_as_float(((unsigned)h) << 16);
  l = f2bf_rne(x - hf);
}

// start[b] = first node index of graph b (batch sorted); start[NB] = NN.
__global__ void k_starts(const int* __restrict__ batch, int* __restrict__ start) {
  int i = blockIdx.x * blockDim.x + threadIdx.x;
  if (i >= NN) return;
  int bi = batch[i];
  int bp = (i == 0) ? -1 : batch[i - 1];
  for (int b = bp + 1; b <= bi; ++b) start[b] = i;
  if (i == NN - 1)
    for (int b = bi + 1; b <= NB; ++b) start[b] = NN;
}

// seq row of token t: metal g -> start[g]+g ; node i -> i + batch[i] + 1
__global__ void k_seqmap(const int* __restrict__ batch, const int* __restrict__ start,
                         int* __restrict__ seqmap) {
  int t = blockIdx.x * 256 + threadIdx.x;
  if (t >= TT) return;
  seqmap[t] = (t < NB) ? (start[t] + t) : (t - NB + batch[t - NB] + 1);
}

// Split weights to hi/lo bf16. Rows: [0,128)Wq | [128,256)Wk | [256,640)in_w | [640,768)out_w
__global__ void k_wconv(const float* __restrict__ Wq, const float* __restrict__ Wk,
                        const float* __restrict__ in_w, const float* __restrict__ out_w,
                        unsigned short* __restrict__ Wh, unsigned short* __restrict__ Wl) {
  int idx = blockIdx.x * 256 + threadIdx.x;
  int r = idx >> 7, c = idx & 127;
  float v;
  if (r < 128)      v = Wq[r * 128 + c];
  else if (r < 256) v = Wk[(r - 128) * 128 + c];
  else if (r < 640) v = in_w[(r - 256) * 128 + c];
  else              v = out_w[(r - 640) * 128 + c];
  unsigned short h, l;
  split_bf(v, h, l);
  Wh[idx] = h;
  Wl[idx] = l;
}

// C = act(A @ W^T + b) [* postscale] via split-bf16 MFMA. 128x128 tile, 4 waves.
template <int AM, int OM, bool RELU>
__global__ __launch_bounds__(256, 2)
void k_gemm(const float* __restrict__ Ax, const float* __restrict__ Am,
            const int* __restrict__ rowmap,
            const unsigned short* __restrict__ Ah, const unsigned short* __restrict__ Al,
            const unsigned short* __restrict__ Wh, const unsigned short* __restrict__ Wl,
            const float* __restrict__ bias, float postscale,
            float* __restrict__ Cx, float* __restrict__ Cm,
            unsigned short* __restrict__ Oh, unsigned short* __restrict__ Ol,
            const int* __restrict__ seqmap) {
  __shared__ char smem[40960];
  float (*Afl)[36] = (float (*)[36])smem;                               // 18432 B (AF32)
  unsigned short (*AshH)[40] = (unsigned short (*)[40])smem;            // 10240 B (ASPLIT)
  unsigned short (*AshL)[40] = (unsigned short (*)[40])(smem + 10240);  // 10240 B
  unsigned short (*WldsH)[40] = (unsigned short (*)[40])(smem + 20480);
  unsigned short (*WldsL)[40] = (unsigned short (*)[40])(smem + 30720);

  const int tid = threadIdx.x;
  const int wave = tid >> 6;
  const int lane = tid & 63;
  const int lrow = lane & 15;
  const int q = lane >> 4;
  const int t0 = blockIdx.x * 128;

  f32x4 acc[2][8];
  #pragma unroll
  for (int mt = 0; mt < 2; ++mt)
    #pragma unroll
    for (int nt = 0; nt < 8; ++nt) acc[mt][nt] = (f32x4){0.f, 0.f, 0.f, 0.f};

  for (int ks = 0; ks < 4; ++ks) {
    __syncthreads();
    if (AM == AF32) {
      #pragma unroll
      for (int u = 0; u < 4; ++u) {
        int e4 = tid + u * 256;
        int m = e4 >> 3, k4 = e4 & 7;
        const float* rp = rowmap ? Ax + (size_t)rowmap[t0 + m] * E
                                 : row_ptr(Ax, Am, t0 + m);
        float4 v = ((const float4*)(rp + ks * 32))[k4];
        *(float4*)&Afl[m][k4 * 4] = v;
      }
    } else {
      #pragma unroll
      for (int u = 0; u < 2; ++u) {
        int e = tid + u * 256;        // [0,512)
        int row = e >> 2, seg = e & 3;
        size_t go = (size_t)(t0 + row) * 128 + ks * 32 + seg * 8;
        *(short8*)&AshH[row][seg * 8] = *(const short8*)(Ah + go);
        *(short8*)&AshL[row][seg * 8] = *(const short8*)(Al + go);
      }
    }
    // W hi/lo slices
    #pragma unroll
    for (int u = 0; u < 4; ++u) {
      int idx = tid + u * 256;
      int half = idx >> 9, rem = idx & 511;
      int j = rem >> 2, seg = rem & 3;
      const unsigned short* src = (half ? Wl : Wh) + j * 128 + ks * 32 + seg * 8;
      short8 v = *(const short8*)src;
      unsigned short* dst = (half ? &WldsL[j][seg * 8] : &WldsH[j][seg * 8]);
      *(short8*)dst = v;
    }
    __syncthreads();

    short8 ah[2], al[2];
    if (AM == AF32) {
      #pragma unroll
      for (int mt = 0; mt < 2; ++mt) {
        int m = wave * 32 + mt * 16 + lrow;
        float4 f0 = *(const float4*)&Afl[m][q * 8];
        float4 f1 = *(const float4*)&Afl[m][q * 8 + 4];
        unsigned short h, l;
        split_bf(f0.x, h, l); ah[mt][0] = (short)h; al[mt][0] = (short)l;
        split_bf(f0.y, h, l); ah[mt][1] = (short)h; al[mt][1] = (short)l;
        split_bf(f0.z, h, l); ah[mt][2] = (short)h; al[mt][2] = (short)l;
        split_bf(f0.w, h, l); ah[mt][3] = (short)h; al[mt][3] = (short)l;
        split_bf(f1.x, h, l); ah[mt][4] = (short)h; al[mt][4] = (short)l;
        split_bf(f1.y, h, l); ah[mt][5] = (short)h; al[mt][5] = (short)l;
        split_bf(f1.z, h, l); ah[mt][6] = (short)h; al[mt][6] = (short)l;
        split_bf(f1.w, h, l); ah[mt][7] = (short)h; al[mt][7] = (short)l;
      }
    } else {
      #pragma unroll
      for (int mt = 0; mt < 2; ++mt) {
        int m = wave * 32 + mt * 16 + lrow;
        ah[mt] = *(const short8*)&AshH[m][q * 8];
        al[mt] = *(const short8*)&AshL[m][q * 8];
      }
    }

    #pragma unroll
    for (int nt = 0; nt < 8; ++nt) {
      int j = nt * 16 + lrow;
      short8 bh = *(const short8*)&WldsH[j][q * 8];
      short8 bl = *(const short8*)&WldsL[j][q * 8];
      #pragma unroll
      for (int mt = 0; mt < 2; ++mt) {
        acc[mt][nt] = __builtin_amdgcn_mfma_f32_16x16x32_bf16(ah[mt], bh, acc[mt][nt], 0, 0, 0);
        acc[mt][nt] = __builtin_amdgcn_mfma_f32_16x16x32_bf16(al[mt], bh, acc[mt][nt], 0, 0, 0);
        acc[mt][nt] = __builtin_amdgcn_mfma_f32_16x16x32_bf16(ah[mt], bl, acc[mt][nt], 0, 0, 0);
      }
    }
  }

  // Epilogue. C/D layout: col = lane&15, row = q*4 + reg.
  #pragma unroll
  for (int mt = 0; mt < 2; ++mt) {
    #pragma unroll
    for (int reg = 0; reg < 4; ++reg) {
      int t = t0 + wave * 32 + mt * 16 + q * 4 + reg;
      float* cp = nullptr;
      size_t ro = 0;
      if (OM == OF32T) cp = row_ptr_w(Cx, Cm, t);
      else if (OM == OSPLITT) ro = (size_t)t * 128;
      else ro = (size_t)seqmap[t] * 128;
      #pragma unroll
      for (int nt = 0; nt < 8; ++nt) {
        int j = nt * 16 + lrow;
        float v = acc[mt][nt][reg] + bias[j];
        if (RELU) v = fmaxf(v, 0.f);
        v *= postscale;
        if (OM == OF32T) {
          cp[j] = v;
        } else if (OM == OBF16SEQ) {
          Oh[ro + j] = f2bf_rne(v);
        } else {
          unsigned short h, l;
          split_bf(v, h, l);
          Oh[ro + j] = h;
          Ol[ro + j] = l;
        }
      }
    }
  }
}

// Flash attention: grid (NB, 6), 4 waves = 4 heads, 32 queries/block.
// Q/K pre-split bf16 seq-order global (scale*log2e folded into Q); V bf16 seq-order.
__global__ __launch_bounds__(256, 3)
void k_flash(const unsigned short* __restrict__ Qh, const unsigned short* __restrict__ Ql,
             const unsigned short* __restrict__ Kh, const unsigned short* __restrict__ Kl,
             const unsigned short* __restrict__ Vb, const int* __restrict__ start,
             float* __restrict__ ctx) {
  __shared__ unsigned short Vlds[32][134];       // 8576 B, odd-word row stride (67 words)
  __shared__ unsigned short Pld[4][2][32][40];   // [wave][hi/lo][row][key] 20480 B
  const int g = blockIdx.x;
  const int tid = threadIdx.x;
  const int wv = tid >> 6;        // head
  const int lane = tid & 63;
  const int lrow = lane & 15;
  const int quad = lane >> 4;
  const int s0 = start[g];
  const int c = start[g + 1] - s0 + 1;   // slots incl. metal at 0
  const int sbase = s0 + g;
  const int hoff = wv * 32 + quad * 8;   // k-dim offset for frags

  for (int qb = 32 * blockIdx.y; qb < c; qb += 32 * gridDim.y) {
    short8 qfh[2], qfl[2];
    #pragma unroll
    for (int mt = 0; mt < 2; ++mt) {
      int qs = qb + mt * 16 + lrow; if (qs >= c) qs = 0;
      size_t off = (size_t)(sbase + qs) * 128 + hoff;
      qfh[mt] = *(const short8*)(Qh + off);
      qfl[mt] = *(const short8*)(Ql + off);
    }
    float mr[2][4], lr[2][4];
    f32x4 O[2][2];
    #pragma unroll
    for (int mt = 0; mt < 2; ++mt) {
      #pragma unroll
      for (int r4 = 0; r4 < 4; ++r4) { mr[mt][r4] = -3.0e38f; lr[mt][r4] = 0.f; }
      O[mt][0] = (f32x4){0.f, 0.f, 0.f, 0.f};
      O[mt][1] = (f32x4){0.f, 0.f, 0.f, 0.f};
    }

    const int nch = (c + 31) >> 5;
    for (int ch = 0; ch < nch; ++ch) {
      const int kb = ch * 32;
      // K B-frags from global (issued early; in flight during V staging)
      short8 kfh[2], kfl[2];
      #pragma unroll
      for (int s = 0; s < 2; ++s) {
        int ks = kb + s * 16 + lrow; if (ks >= c) ks = 0;
        size_t off = (size_t)(sbase + ks) * 128 + hoff;
        kfh[s] = *(const short8*)(Kh + off);
        kfl[s] = *(const short8*)(Kl + off);
      }
      __syncthreads();   // previous chunk's Vlds reads complete
      // stage V chunk (32 keys x 128 dims bf16), row-major, odd-word stride
      #pragma unroll
      for (int r = 0; r < 2; ++r) {
        int key = r * 16 + (tid >> 4);
        int seg = tid & 15;
        int ks = kb + key; if (ks >= c) ks = 0;
        uint4 v = *(const uint4*)(Vb + (size_t)(sbase + ks) * 128 + seg * 8);
        unsigned* dst = (unsigned*)&Vlds[key][seg * 8];   // 4B-aligned
        dst[0] = v.x; dst[1] = v.y; dst[2] = v.z; dst[3] = v.w;
      }
      __syncthreads();

      // QK^T: split-bf16 (3 MFMA per 16x16 tile)
      f32x4 sv[2][2];
      #pragma unroll
      for (int mt = 0; mt < 2; ++mt)
        #pragma unroll
        for (int s = 0; s < 2; ++s) {
          f32x4 z = (f32x4){0.f, 0.f, 0.f, 0.f};
          z = __builtin_amdgcn_mfma_f32_16x16x32_bf16(qfh[mt], kfh[s], z, 0, 0, 0);
          z = __builtin_amdgcn_mfma_f32_16x16x32_bf16(qfl[mt], kfh[s], z, 0, 0, 0);
          z = __builtin_amdgcn_mfma_f32_16x16x32_bf16(qfh[mt], kfl[s], z, 0, 0, 0);
          sv[mt][s] = z;
        }
      const bool v0 = (kb + lrow) < c;
      const bool v1 = (kb + 16 + lrow) < c;

      #pragma unroll
      for (int mt = 0; mt < 2; ++mt) {
        float mn[4], al[4], p0[4], p1[4], rs[4];
        #pragma unroll
        for (int r4 = 0; r4 < 4; ++r4) {
          float a = v0 ? sv[mt][0][r4] : -3.0e38f;
          float b = v1 ? sv[mt][1][r4] : -3.0e38f;
          sv[mt][0][r4] = a; sv[mt][1][r4] = b;
          mn[r4] = fmaxf(mr[mt][r4], fmaxf(a, b));
        }
        #pragma unroll
        for (int st = 1; st < 16; st <<= 1)
          #pragma unroll
          for (int r4 = 0; r4 < 4; ++r4)
            mn[r4] = fmaxf(mn[r4], __shfl_xor(mn[r4], st, 16));
        #pragma unroll
        for (int r4 = 0; r4 < 4; ++r4) {
          al[r4] = exp2f(mr[mt][r4] - mn[r4]);
          p0[r4] = exp2f(sv[mt][0][r4] - mn[r4]);
          p1[r4] = exp2f(sv[mt][1][r4] - mn[r4]);
          rs[r4] = p0[r4] + p1[r4];
          mr[mt][r4] = mn[r4];
        }
        #pragma unroll
        for (int st = 1; st < 16; st <<= 1)
          #pragma unroll
          for (int r4 = 0; r4 < 4; ++r4)
            rs[r4] += __shfl_xor(rs[r4], st, 16);
        #pragma unroll
        for (int r4 = 0; r4 < 4; ++r4) {
          lr[mt][r4] = lr[mt][r4] * al[r4] + rs[r4];
          int row = mt * 16 + quad * 4 + r4;
          unsigned short h, l;
          split_bf(p0[r4], h, l);
          Pld[wv][0][row][lrow] = h; Pld[wv][1][row][lrow] = l;
          split_bf(p1[r4], h, l);
          Pld[wv][0][row][lrow + 16] = h; Pld[wv][1][row][lrow + 16] = l;
          O[mt][0][r4] *= al[r4];
          O[mt][1][r4] *= al[r4];
        }
      }

      // V B-frags (scalar u16 reads, Vlds transposed access)
      short8 vf[2];
      #pragma unroll
      for (int nt = 0; nt < 2; ++nt)
        #pragma unroll
        for (int jj = 0; jj < 8; ++jj)
          vf[nt][jj] = (short)Vlds[quad * 8 + jj][wv * 32 + nt * 16 + lrow];

      // PV: O += (Ph + Pl) * V
      #pragma unroll
      for (int mt = 0; mt < 2; ++mt) {
        short8 ph = *(const short8*)&Pld[wv][0][mt * 16 + lrow][quad * 8];
        short8 pl = *(const short8*)&Pld[wv][1][mt * 16 + lrow][quad * 8];
        #pragma unroll
        for (int nt = 0; nt < 2; ++nt) {
          O[mt][nt] = __builtin_amdgcn_mfma_f32_16x16x32_bf16(ph, vf[nt], O[mt][nt], 0, 0, 0);
          O[mt][nt] = __builtin_amdgcn_mfma_f32_16x16x32_bf16(pl, vf[nt], O[mt][nt], 0, 0, 0);
        }
      }
    }

    // store ctx (fp32, seq order). C/D: row(query) = quad*4+reg, col(dim) = lrow
    #pragma unroll
    for (int mt = 0; mt < 2; ++mt)
      #pragma unroll
      for (int r4 = 0; r4 < 4; ++r4) {
        int qs = qb + mt * 16 + quad * 4 + r4;
        if (qs < c) {
          float inv = 1.f / lr[mt][r4];
          float* cp = ctx + (size_t)(sbase + qs) * 128 + wv * 32 + lrow;
          cp[0]  = O[mt][0][r4] * inv;
          cp[16] = O[mt][1][r4] * inv;
        }
      }
  }
}

extern "C" void kernel_launch(void* const* d_in, const int* in_sizes, int n_in,
                              void* d_out, int out_size, void* d_ws, size_t ws_size,
                              hipStream_t stream) {
  const float* x       = (const float*)d_in[0];
  const float* metal_x = (const float*)d_in[1];
  const int*   batch   = (const int*)d_in[2];
  const float* Wk      = (const float*)d_in[3];
  const float* bk      = (const float*)d_in[4];
  const float* Wq      = (const float*)d_in[5];
  const float* bq      = (const float*)d_in[6];
  const float* in_w    = (const float*)d_in[7];
  const float* in_b    = (const float*)d_in[8];
  const float* out_w   = (const float*)d_in[9];
  const float* out_b   = (const float*)d_in[10];
  float* out = (float*)d_out;

  // ---- workspace layout (float offsets) ----
  // [0,528)            start (513 ints, padded)
  // [528,66576)        seqmap (66048 ints)
  // [66576,164880)     Wh+Wl  (2 x 98304 shorts = 98304 FLOATS total — both halves!)
  // [164880, ...)      big buffers
  float* ws = (float*)d_ws;
  int* start  = (int*)d_ws;
  int* seqmap = (int*)(ws + 528);
  unsigned short* Wh = (unsigned short*)(ws + 66576);
  unsigned short* Wl = Wh + 768 * 128;
  const size_t BUF0 = 164880;   // = 66576 + 98304  (after BOTH weight halves)
  unsigned short* Hkh = (unsigned short*)(ws + BUF0);        // Hk pair (TE floats)
  unsigned short* Hkl = Hkh + TE;
  float* ctx = ws + BUF0;                                    // reuses Hk slot after K-GEMM
  unsigned short* Qsh = (unsigned short*)(ws + BUF0 + TE);
  unsigned short* Qsl = Qsh + TE;
  unsigned short* Ksh = (unsigned short*)(ws + BUF0 + 2 * TE);
  unsigned short* Ksl = Ksh + TE;
  unsigned short* Vsb = (unsigned short*)(ws + BUF0 + 3 * TE);   // bf16 only (TE/2 floats)
  // peak ws = (164880 + 3.5*TE)*4 B ~= 119.0 MB  (< 135.3 MB known-good)
  unsigned short* Hqh = (unsigned short*)d_out;   // Hq pair staged in d_out (TE floats exact)
  unsigned short* Hql = Hqh + TE;

  k_starts<<<NN / 256, 256, 0, stream>>>(batch, start);
  k_seqmap<<<TT / 256, 256, 0, stream>>>(batch, start, seqmap);
  k_wconv<<<768 * 128 / 256, 256, 0, stream>>>(Wq, Wk, in_w, out_w, Wh, Wl);

  const int gb = TT / 128;  // 516
  const float SCL2 = 0.17677669529663687f * 1.4426950408889634f;  // scale*log2(e)
  // V = x@in_w_v^T + b  -> bf16 seq
  k_gemm<AF32, OBF16SEQ, false><<<gb, 256, 0, stream>>>(
      x, metal_x, nullptr, nullptr, nullptr, Wh + 512 * 128, Wl + 512 * 128,
      in_b + 2 * E, 1.f, nullptr, nullptr, Vsb, nullptr, seqmap);
  // Hq = relu(x@Wq^T + bq) -> split pair (token order, in d_out)
  k_gemm<AF32, OSPLITT, true><<<gb, 256, 0, stream>>>(
      x, metal_x, nullptr, nullptr, nullptr, Wh, Wl,
      bq, 1.f, nullptr, nullptr, Hqh, Hql, nullptr);
  // Hk = relu(x@Wk^T + bk) -> split pair (token order)
  k_gemm<AF32, OSPLITT, true><<<gb, 256, 0, stream>>>(
      x, metal_x, nullptr, nullptr, nullptr, Wh + 128 * 128, Wl + 128 * 128,
      bk, 1.f, nullptr, nullptr, Hkh, Hkl, nullptr);
  // Q = Hq@in_w_q^T + b, scaled by scale*log2e -> split pair, seq order
  k_gemm<ASPLIT, OSPLITSEQ, false><<<gb, 256, 0, stream>>>(
      nullptr, nullptr, nullptr, Hqh, Hql, Wh + 256 * 128, Wl + 256 * 128,
      in_b, SCL2, nullptr, nullptr, Qsh, Qsl, seqmap);
  // K = Hk@in_w_k^T + b -> split pair, seq order
  k_gemm<ASPLIT, OSPLITSEQ, false><<<gb, 256, 0, stream>>>(
      nullptr, nullptr, nullptr, Hkh, Hkl, Wh + 384 * 128, Wl + 384 * 128,
      in_b + 128, 1.f, nullptr, nullptr, Ksh, Ksl, seqmap);

  dim3 agrid(NB, 6);
  k_flash<<<agrid, 256, 0, stream>>>(Qsh, Qsl, Ksh, Ksl, Vsb, start, ctx);

  // out = ctx@out_w^T + b (A gathered via seqmap), token-order output
  k_gemm<AF32, OF32T, false><<<gb, 256, 0, stream>>>(
      ctx, nullptr, seqmap, nullptr, nullptr, Wh + 640 * 128, Wl + 640 * 128,
      out_b, 1.f, out, out + (size_t)NN * E, nullptr, nullptr, nullptr);
}